// Round 1
// baseline (560.469 us; speedup 1.0000x reference)
//
#include <hip/hip_runtime.h>
#include <hip/hip_bf16.h>
#include <cstdint>
#include <cstddef>

// ---------------- types / helpers ----------------
typedef __bf16 bf16x8 __attribute__((ext_vector_type(8)));
typedef __bf16 bf16x4 __attribute__((ext_vector_type(4)));
typedef float  floatx4 __attribute__((ext_vector_type(4)));

#define DEV __device__ __forceinline__

DEV __bf16 f2b(float x) { return (__bf16)x; }

// async global->LDS, 16B per lane. LDS dest semantics: wave-uniform base + lane*16.
DEV void async_ld16(const void* g, void* l) {
    __builtin_amdgcn_global_load_lds(
        (const __attribute__((address_space(1))) unsigned int*)g,
        (__attribute__((address_space(3))) unsigned int*)l,
        16, 0, 0);
}

// ---------------- constants ----------------
#define BATCH 4096
#define DDIM  4624          // 68*68
#define DPAD  4800          // GEMM1 K padded to mult of 192 (75*64, 3-buffer pipeline)
#define LDIM  68
#define EDIM  1024
#define N1    2048          // fc11|fc12 fused
#define KB    2048          // stage-B K (h11|h12)
#define N2PAD 4864          // 19*256
#define NPAIR 2346          // 68*69/2 symmetric pairs
#define K2PAD 2496          // NPAIR padded: 39*64 (mult of 192)

// ======================================================================
// fp32 -> bf16 convert with zero padding. dst[rows_total][DPAD].
// ======================================================================
__global__ void cvt_pad(const float* __restrict__ src, int rows_valid, int K,
                        __bf16* __restrict__ dst, int rows_total) {
    const int gpr = DPAD / 4;   // 1200
    const long total = (long)rows_total * gpr;
    for (long g = blockIdx.x * (long)blockDim.x + threadIdx.x; g < total;
         g += gridDim.x * (long)blockDim.x) {
        int row = (int)(g / gpr);
        int c4  = (int)(g - (long)row * gpr) * 4;
        bf16x4 v;
        if (row < rows_valid && c4 < K) {
            floatx4 f = *(const floatx4*)(src + (size_t)row * K + c4);
            v[0] = f2b(f[0]); v[1] = f2b(f[1]); v[2] = f2b(f[2]); v[3] = f2b(f[3]);
        } else {
            v[0] = v[1] = v[2] = v[3] = (__bf16)0.0f;
        }
        *(bf16x4*)(dst + (size_t)row * DPAD + c4) = v;
    }
}

// w2_pad [144][2048] bf16: rows 0..67 = fc21 in cols 0..1023; rows 68..135 = fc22 in
// cols 1024..2047; everything else 0. (matches hbuf layout h11|h12)
__global__ void pad_w2(const float* __restrict__ w21, const float* __restrict__ w22,
                       __bf16* __restrict__ dst) {
    const int total = 144 * 512;
    for (int g = blockIdx.x * blockDim.x + threadIdx.x; g < total;
         g += gridDim.x * blockDim.x) {
        int row = g >> 9;
        int c4  = (g & 511) * 4;
        bf16x4 v;
        v[0] = v[1] = v[2] = v[3] = (__bf16)0.0f;
        if (row < 68 && c4 < 1024) {
            floatx4 f = *(const floatx4*)(w21 + (size_t)row * EDIM + c4);
            v[0] = f2b(f[0]); v[1] = f2b(f[1]); v[2] = f2b(f[2]); v[3] = f2b(f[3]);
        } else if (row >= 68 && row < 136 && c4 >= 1024) {
            floatx4 f = *(const floatx4*)(w22 + (size_t)(row - 68) * EDIM + (c4 - 1024));
            v[0] = f2b(f[0]); v[1] = f2b(f[1]); v[2] = f2b(f[2]); v[3] = f2b(f[3]);
        }
        *(bf16x4*)(dst + (size_t)row * KB + c4) = v;
    }
}

// ======================================================================
// pair table: p -> (i,j), i<=j, p = i*(137-i)/2 + (j-i). Built in LDS.
// ======================================================================
DEV void build_ptab(unsigned short* ptab, int t, int nthr) {
    for (int i = t; i < LDIM; i += nthr) {
        int p0 = i * (137 - i) / 2;
        for (int j = i; j < LDIM; ++j)
            ptab[p0 + (j - i)] = (unsigned short)((i << 8) | j);
    }
}

// ======================================================================
// w6sym: one block per output row o. dst[o][p] = w6[o][i,j] + w6[o][j,i] (i<j),
// w6[o][i,i] (i==j); zero pad for p>=NPAIR and o>=DDIM.
// ======================================================================
__global__ void w6sym_build(const float* __restrict__ w6, __bf16* __restrict__ dst) {
    __shared__ float row[DDIM];
    __shared__ unsigned short ptab[K2PAD];
    const int o = blockIdx.x;
    const int t = threadIdx.x;
    if (o < DDIM) {
        const float* src = w6 + (size_t)o * DDIM;
        for (int idx = t; idx < DDIM / 4; idx += 256)
            *(floatx4*)(row + idx * 4) = *(const floatx4*)(src + idx * 4);
    }
    build_ptab(ptab, t, 256);
    __syncthreads();
    for (int p4 = t; p4 < K2PAD / 4; p4 += 256) {
        bf16x4 v;
#pragma unroll
        for (int u = 0; u < 4; ++u) {
            int p = p4 * 4 + u;
            float val = 0.f;
            if (o < DDIM && p < NPAIR) {
                int ij = ptab[p];
                int i = ij >> 8, j = ij & 255;
                val = (i == j) ? row[i * LDIM + i] : (row[i * LDIM + j] + row[j * LDIM + i]);
            }
            v[u] = f2b(val);
        }
        *(bf16x4*)(dst + (size_t)o * K2PAD + p4 * 4) = v;
    }
}

// ======================================================================
// main MFMA GEMM: C[M,N] = epi(A[M,K] * W[N,K]^T + bias)
// BM=128 x BN=256 tile, BK=64, 8 waves (each 64x64 via 4x4 frags of 16x16x32).
// TRIPLE-buffered LDS (144 KiB), prefetch distance 2 K-tiles, ONE raw s_barrier
// + ONE counted s_waitcnt vmcnt(6) per K-tile (never drained to 0 in the main
// loop -> loads stay in flight across barriers, T3/T4). setprio around MFMA
// clusters (T5). Chunk XOR-swizzle (chunk ^ (row&7)) applied on the GLOBAL-side
// address (m104/m108: global_load_lds dest must be linear) so frag ds_read_b128s
// are <=2-way bank-aliased (free, m136). KT must be a multiple of 3.
// EPI 0: relu(acc + (col<1024 ? b0[col] : b1[col-1024])) -> bf16 outb
// EPI 1: sigmoid(acc + b0[col]) -> fp32 outf, only col < DDIM
// ======================================================================
template <int EPI>
__launch_bounds__(512, 1)
__global__ void gemm_bt(const __bf16* __restrict__ A, int lda,
                        const __bf16* __restrict__ W, int ldb, int KT,
                        __bf16* __restrict__ outb, float* __restrict__ outf, int ldc,
                        const float* __restrict__ bias0, const float* __restrict__ bias1) {
    __shared__ __align__(16) __bf16 smA[3 * 128 * 64];   // 48 KB (3 x 16 KB)
    __shared__ __align__(16) __bf16 smB[3 * 256 * 64];   // 96 KB (3 x 32 KB)

    const int t  = threadIdx.x;
    const int l  = t & 63;
    const int w  = t >> 6;
    const int m0 = blockIdx.x * 128;
    const int n0 = blockIdx.y * 256;
    const int wm = (w & 1) * 64;          // 2 M-waves
    const int wn = (w >> 1) * 64;         // 4 N-waves

    // ---- staging setup: per K-tile, A needs 2 rounds of 512x16B, B needs 4.
    // round r covers local rows [r*64, r*64+64); thread t -> row r*64 + (t>>3),
    // LDS 16B-chunk (t&7) at linear dest t*16 + r*8192; global chunk is the
    // XOR-swizzled (t&7)^(row&7).
    const int lr = t >> 3;                               // 0..63
    const int sw = (t & 7) ^ (lr & 7);                   // swizzled global chunk
    const __bf16* pa0 = A + (size_t)(m0 + lr) * lda + sw * 8;
    const __bf16* pb0 = W + (size_t)(n0 + lr) * ldb + sw * 8;
    char* dA = (char*)smA + t * 16;
    char* dB = (char*)smB + t * 16;

    // ---- frag-read setup (byte offsets within one buffer)
    const int q  = l >> 4;                // 0..3
    const int ra = wm + (l & 15);         // A row base (add mi*16)
    const int rb = wn + (l & 15);         // B row base (add ni*16)

    floatx4 acc[4][4];
#pragma unroll
    for (int mi = 0; mi < 4; ++mi)
#pragma unroll
        for (int ni = 0; ni < 4; ++ni) {
            floatx4 z = {0.f, 0.f, 0.f, 0.f};
            acc[mi][ni] = z;
        }

    auto STAGE = [&](int tile, int buf) {
        const __bf16* sa = pa0 + (size_t)tile * 64;
        const __bf16* sb = pb0 + (size_t)tile * 64;
        char* da = dA + buf * 16384;
        char* db = dB + buf * 32768;
        async_ld16(sa,                        da);
        async_ld16(sa + (size_t)64  * lda,    da + 8192);
        async_ld16(sb,                        db);
        async_ld16(sb + (size_t)64  * ldb,    db + 8192);
        async_ld16(sb + (size_t)128 * ldb,    db + 16384);
        async_ld16(sb + (size_t)192 * ldb,    db + 24576);
    };

    auto COMPUTE = [&](int ba, int bb) {   // byte offsets of buffers (constants)
        const char* baseA = (const char*)smA + ba;
        const char* baseB = (const char*)smB + bb;
#pragma unroll
        for (int h = 0; h < 2; ++h) {
            const int c = ((h << 2) | q) ^ (l & 7);      // swizzled chunk
            bf16x8 af[4], bfr[4];
#pragma unroll
            for (int mi = 0; mi < 4; ++mi)
                af[mi] = *(const bf16x8*)(baseA + (ra + mi * 16) * 128 + c * 16);
#pragma unroll
            for (int ni = 0; ni < 4; ++ni)
                bfr[ni] = *(const bf16x8*)(baseB + (rb + ni * 16) * 128 + c * 16);
            __builtin_amdgcn_s_setprio(1);
#pragma unroll
            for (int mi = 0; mi < 4; ++mi)
#pragma unroll
                for (int ni = 0; ni < 4; ++ni)
                    acc[mi][ni] = __builtin_amdgcn_mfma_f32_16x16x32_bf16(
                        af[mi], bfr[ni], acc[mi][ni], 0, 0, 0);
            __builtin_amdgcn_s_setprio(0);
        }
    };

// one K-tile body: counted-vmcnt wait (tile's loads were issued 2 tiles ago),
// raw barrier (no compiler vmcnt(0) drain), pinned stage issue, then compute.
#define GBODY(BA, BB, DOSTG, STGT, STGBUF, VMS)                         \
    {                                                                   \
        asm volatile("s_waitcnt vmcnt(" VMS ")" ::: "memory");          \
        __builtin_amdgcn_s_barrier();                                   \
        __builtin_amdgcn_sched_barrier(0);                              \
        if (DOSTG) STAGE(STGT, STGBUF);                                 \
        COMPUTE(BA, BB);                                                \
    }

    // prologue: 2 K-tiles in flight (12 vm ops)
    STAGE(0, 0);
    STAGE(1, 1);

    int kt = 0;
    for (; kt < KT - 3; kt += 3) {
        GBODY(0,     0,     true, kt + 2, 2, "6");
        GBODY(16384, 32768, true, kt + 3, 0, "6");
        GBODY(32768, 65536, true, kt + 4, 1, "6");
    }
    // last group (kt == KT-3): drain
    GBODY(0,     0,     true,  kt + 2, 2, "6");
    GBODY(16384, 32768, false, 0,      0, "6");
    GBODY(32768, 65536, false, 0,      0, "0");
#undef GBODY

    // epilogue: C/D layout col = lane&15, row = (lane>>4)*4 + reg  [m89/m91]
    const int colbase = n0 + wn + (l & 15);
    const int rowbase = m0 + wm + (l >> 4) * 4;
#pragma unroll
    for (int ni = 0; ni < 4; ++ni) {
        int col = colbase + ni * 16;
        if (EPI == 1 && col >= DDIM) continue;
        float bias = (EPI == 0)
                         ? ((col < 1024) ? bias0[col] : bias1[col - 1024])
                         : bias0[col];
#pragma unroll
        for (int mi = 0; mi < 4; ++mi) {
            int row = rowbase + mi * 16;
#pragma unroll
            for (int r = 0; r < 4; ++r) {
                float v = acc[mi][ni][r] + bias;
                if (EPI == 0) {
                    v = v > 0.f ? v : 0.f;
                    outb[(size_t)(row + r) * ldc + col] = f2b(v);
                } else {
                    v = 1.f / (1.f + __expf(-v));
                    outf[(size_t)(row + r) * ldc + col] = v;
                }
            }
        }
    }
}

// ======================================================================
// stage B: muvar[4096][136] += h[4096][2048] * w2_pad[144][2048]^T (K-split x4, atomics)
// ======================================================================
__launch_bounds__(64, 4)
__global__ void gemmB(const __bf16* __restrict__ h, const __bf16* __restrict__ w2,
                      float* __restrict__ muvar) {
    const int l    = threadIdx.x;
    const int m0   = blockIdx.x * 16;
    const int k0   = blockIdx.y * 512;
    const int row  = l & 15;
    const int quad = l >> 4;

    floatx4 acc[9];
#pragma unroll
    for (int ni = 0; ni < 9; ++ni) {
        floatx4 z = {0.f, 0.f, 0.f, 0.f};
        acc[ni] = z;
    }

    const __bf16* ap = h + (size_t)(m0 + row) * KB + k0 + quad * 8;
    for (int kt = 0; kt < 16; ++kt) {
        bf16x8 a = *(const bf16x8*)ap;
        ap += 32;
#pragma unroll
        for (int ni = 0; ni < 9; ++ni) {
            const __bf16* bp = w2 + (size_t)(ni * 16 + row) * KB + k0 + kt * 32 + quad * 8;
            bf16x8 b = *(const bf16x8*)bp;
            acc[ni] = __builtin_amdgcn_mfma_f32_16x16x32_bf16(a, b, acc[ni], 0, 0, 0);
        }
    }
#pragma unroll
    for (int ni = 0; ni < 9; ++ni) {
        int col = ni * 16 + row;
        if (col < 136) {
#pragma unroll
            for (int r = 0; r < 4; ++r) {
                int orow = m0 + quad * 4 + r;
                atomicAdd(&muvar[(size_t)orow * 136 + col], acc[ni][r]);
            }
        }
    }
}

// ======================================================================
// decode (fp32): mu/logvar(+bias) -> z -> h3_0 -> h4_0 -> h51 -> symmetric-pair A2
// also writes mu, logvar, y. Branches 1..4 dead (recon uses h51 only).
// ======================================================================
__global__ void decode(const float* __restrict__ muvar, const float* __restrict__ eps,
                       const float* __restrict__ b21, const float* __restrict__ b22,
                       const float* __restrict__ W3, const float* __restrict__ b3,
                       const float* __restrict__ W4, const float* __restrict__ b4,
                       const float* __restrict__ W5, const float* __restrict__ b5,
                       const float* __restrict__ fcyw, const float* __restrict__ fcyb,
                       float* __restrict__ out_mu, float* __restrict__ out_lv,
                       float* __restrict__ out_y, __bf16* __restrict__ A2) {
    __shared__ float w3s[DDIM], w4s[DDIM], w5s[DDIM];
    __shared__ float b3s[LDIM], b4s[LDIM], b5s[LDIM], fys[LDIM];
    __shared__ float zb[16][LDIM], h3b[16][LDIM], h51b[16][LDIM];
    __shared__ unsigned short ptab[K2PAD];

    const int t  = threadIdx.x;
    const int r0 = blockIdx.x * 16;

    for (int i = t; i < DDIM; i += 256) {  // branch 0 = first 68*68 of each tensor
        w3s[i] = W3[i];
        w4s[i] = W4[i];
        w5s[i] = W5[i];
    }
    if (t < LDIM) {
        b3s[t] = b3[t];
        b4s[t] = b4[t];
        b5s[t] = b5[t];
        fys[t] = fcyw[t];
    }
    build_ptab(ptab, t, 256);
    __syncthreads();

    for (int idx = t; idx < 16 * LDIM; idx += 256) {
        int r = idx / LDIM, o = idx - r * LDIM;
        int row = r0 + r;
        float mu = muvar[(size_t)row * 136 + o] + b21[o];
        float lv = muvar[(size_t)row * 136 + 68 + o] + b22[o];
        float z  = mu + eps[(size_t)row * LDIM + o] * __expf(0.5f * lv);
        zb[r][o] = z;
        out_mu[(size_t)row * LDIM + o] = mu;
        out_lv[(size_t)row * LDIM + o] = lv;
    }
    if (t < 16) {
        int row = r0 + t;
        float s = fcyb[0];
        for (int o = 0; o < LDIM; ++o)
            s += (muvar[(size_t)row * 136 + o] + b21[o]) * fys[o];
        out_y[row] = s;
    }
    __syncthreads();

    // h3_0 = z @ W3_0^T + b3_0   (branch 0: NO sigmoid)
    for (int idx = t; idx < 16 * LDIM; idx += 256) {
        int r = idx / LDIM, o = idx - r * LDIM;
        float s = b3s[o];
        for (int d = 0; d < LDIM; ++d) s += zb[r][d] * w3s[o * LDIM + d];
        h3b[r][o] = s;
    }
    __syncthreads();

    // h4_0 = sigmoid(h3_0 @ W4_0^T + b4_0)  -> reuse zb
    for (int idx = t; idx < 16 * LDIM; idx += 256) {
        int r = idx / LDIM, o = idx - r * LDIM;
        float s = b4s[o];
        for (int d = 0; d < LDIM; ++d) s += h3b[r][d] * w4s[o * LDIM + d];
        zb[r][o] = 1.f / (1.f + __expf(-s));
    }
    __syncthreads();

    // h51 = h4_0 @ W5_0^T + b5_0
    for (int idx = t; idx < 16 * LDIM; idx += 256) {
        int r = idx / LDIM, o = idx - r * LDIM;
        float s = b5s[o];
        for (int d = 0; d < LDIM; ++d) s += zb[r][d] * w5s[o * LDIM + d];
        h51b[r][o] = s;
    }
    __syncthreads();

    // symmetric-pair "outer product": A2[row][p] = h51[i]*h51[j] (factor 2 folded into w6sym)
    for (int idx = t; idx < 16 * (K2PAD / 4); idx += 256) {
        int r  = idx / (K2PAD / 4);
        int p4 = (idx - r * (K2PAD / 4)) * 4;
        int row = r0 + r;
        bf16x4 v;
#pragma unroll
        for (int u = 0; u < 4; ++u) {
            int p = p4 + u;
            float val = 0.f;
            if (p < NPAIR) {
                int ij = ptab[p];
                val = h51b[r][ij >> 8] * h51b[r][ij & 255];
            }
            v[u] = f2b(val);
        }
        *(bf16x4*)(A2 + (size_t)row * K2PAD + p4) = v;
    }
}

// ======================================================================
extern "C" void kernel_launch(void* const* d_in, const int* in_sizes, int n_in,
                              void* d_out, int out_size, void* d_ws, size_t ws_size,
                              hipStream_t stream) {
    const float* x    = (const float*)d_in[0];
    const float* eps  = (const float*)d_in[1];
    const float* w11  = (const float*)d_in[2];
    const float* b11  = (const float*)d_in[3];
    const float* w12  = (const float*)d_in[4];
    const float* b12  = (const float*)d_in[5];
    const float* w21  = (const float*)d_in[6];
    const float* b21  = (const float*)d_in[7];
    const float* w22  = (const float*)d_in[8];
    const float* b22  = (const float*)d_in[9];
    const float* W3   = (const float*)d_in[10];
    const float* b3   = (const float*)d_in[11];
    const float* W4   = (const float*)d_in[12];
    const float* b4   = (const float*)d_in[13];
    const float* W5   = (const float*)d_in[14];
    const float* b5   = (const float*)d_in[15];
    const float* w6   = (const float*)d_in[16];
    const float* b6   = (const float*)d_in[17];
    const float* fcyw = (const float*)d_in[18];
    const float* fcyb = (const float*)d_in[19];

    float* out       = (float*)d_out;
    float* out_recon = out;
    float* out_mu    = out + (size_t)BATCH * DDIM;
    float* out_lv    = out_mu + (size_t)BATCH * LDIM;
    float* out_y     = out_lv + (size_t)BATCH * LDIM;

    // ws layout (bytes, 256B-aligned)
    char* ws = (char*)d_ws;
    size_t off = 0;
    __bf16* xb     = (__bf16*)(ws + off); off += (size_t)BATCH * DPAD * 2;   // 39.3 MB
    __bf16* w1_pad = (__bf16*)(ws + off); off += (size_t)N1 * DPAD * 2;      // 19.7 MB
    __bf16* w6s    = (__bf16*)(ws + off); off += (size_t)N2PAD * K2PAD * 2;  // 24.3 MB
    __bf16* hbuf   = (__bf16*)(ws + off); off += (size_t)BATCH * KB * 2;     // 16.8 MB
    __bf16* w2_pad = (__bf16*)(ws + off); off += (size_t)144 * KB * 2;       //  0.6 MB
    float*  muvar  = (float*) (ws + off); off += (size_t)BATCH * 136 * 4;    //  2.2 MB
    __bf16* A2     = (__bf16*)(ws + off);                                    // 20.4 MB
    // total ~123 MB

    hipMemsetAsync(muvar, 0, (size_t)BATCH * 136 * 4, stream);

    // fp32 -> zero-padded bf16 staging buffers
    cvt_pad<<<2048, 256, 0, stream>>>(x, BATCH, DDIM, xb, BATCH);
    cvt_pad<<<512, 256, 0, stream>>>(w11, 1024, DDIM, w1_pad, 1024);
    cvt_pad<<<512, 256, 0, stream>>>(w12, 1024, DDIM, w1_pad + (size_t)1024 * DPAD, 1024);
    w6sym_build<<<N2PAD, 256, 0, stream>>>(w6, w6s);
    pad_w2<<<72, 256, 0, stream>>>(w21, w22, w2_pad);

    // GEMM1: h = relu(x @ [fc11|fc12]^T + b)   M=4096 N=2048 K=4800 (KT=75)
    gemm_bt<0><<<dim3(BATCH / 128, N1 / 256), 512, 0, stream>>>(
        xb, DPAD, w1_pad, DPAD, DPAD / 64, hbuf, nullptr, N1, b11, b12);

    // stage B: muvar = h @ w2_pad^T (K-split, atomics)
    gemmB<<<dim3(BATCH / 16, 4), 64, 0, stream>>>(hbuf, w2_pad, muvar);

    // decode + symmetric-pair A2 (bf16, zero-padded)
    decode<<<BATCH / 16, 256, 0, stream>>>(muvar, eps, b21, b22, W3, b3, W4, b4, W5, b5,
                                           fcyw, fcyb, out_mu, out_lv, out_y, A2);

    // GEMM2: recon = sigmoid(A2sym @ w6sym^T + b6)  M=4096 N=4864(valid 4624) K=2496 (KT=39)
    gemm_bt<1><<<dim3(BATCH / 128, N2PAD / 256), 512, 0, stream>>>(
        A2, K2PAD, w6s, K2PAD, K2PAD / 64, nullptr, out_recon, DDIM, b6, nullptr);
}